// Round 5
// baseline (290.891 us; speedup 1.0000x reference)
//
#include <hip/hip_runtime.h>
#include <stdint.h>

#define NB 8192          // coarse buckets (top 13 bits of monotone key)
#define BSHIFT 19
#define HS 512
#define HM 511
#define CAP 4096         // candidate capacity
#define CAP2 6144        // optimistic capture capacity (= 6*NT, 24 KB as u32)
#define PCAP 2048        // pruned-candidate capacity
#define NRB 2048         // refined buckets
#define NT 1024
#define CAPTHR 1.75f     // capture threshold (raw-logit space)

typedef unsigned long long ull;

// ---- raw barrier, LDS-ordering only: does NOT drain vmcnt, so global
// stores issued earlier stay in flight across it (validated counted-vmcnt
// pattern: producer-side lgkmcnt(0) BEFORE s_barrier; sched_barrier stops
// the scheduler hoisting dependent ops above the wait). ----
__device__ __forceinline__ void bar_lds() {
    asm volatile("s_waitcnt lgkmcnt(0)" ::: "memory");
    __builtin_amdgcn_s_barrier();
    __builtin_amdgcn_sched_barrier(0);
}
// ---- full barrier: drains vmcnt too (orders zero-stores before scatter) ----
__device__ __forceinline__ void bar_full() {
    asm volatile("s_waitcnt vmcnt(0) lgkmcnt(0)" ::: "memory");
    __builtin_amdgcn_s_barrier();
    __builtin_amdgcn_sched_barrier(0);
}

// ---- monotonic float<->uint mapping: larger float => larger uint ----
__device__ __forceinline__ unsigned mono_u32(float x) {
    unsigned b = __float_as_uint(x);
    return (b & 0x80000000u) ? ~b : (b | 0x80000000u);
}
__device__ __forceinline__ float inv_mono(unsigned u) {
    unsigned b = (u & 0x80000000u) ? (u & 0x7fffffffu) : ~u;
    return __uint_as_float(b);
}

// numpy op order: pen = freq*cnt + pres*(cnt>0); x = (l - pen) / t
__device__ __forceinline__ float compute_x(float l, int cnt,
                                           float pres, float freq, float t) {
    float pen = __fadd_rn(__fmul_rn(freq, (float)cnt), (cnt > 0) ? pres : 0.0f);
    return __fdiv_rn(__fsub_rn(l, pen), t);
}

__global__ __launch_bounds__(NT) void k_fused(
    const float* __restrict__ logits, const int* __restrict__ tokens,
    const float* __restrict__ pres_v, const float* __restrict__ freq_v,
    const float* __restrict__ temps, const float* __restrict__ topp_v,
    const int* __restrict__ topk_v, int V, int H, float* __restrict__ out)
{
    // ---- 60 KB LDS, phase-wise region reuse (validated budget) ----
    __shared__ __align__(16) char smem[(32 + 16 + 8 + 4) * 1024];
    unsigned* hc = (unsigned*)smem;              // A: coarse hist (phases A,B)
    ull* skey = (ull*)smem;                      // A alias: candidates (C..F)
    char* regB = smem + 32 * 1024;               // 16 KB
    float* se = (float*)regB;                    //   phase F exp values
    ull* tmpc = (ull*)regB;                      //   phase D compaction buffer
    char* regC = smem + 48 * 1024;               // 8 KB
    unsigned* rh = (unsigned*)regC;              //   phase D refined hist
    unsigned* cbuf = (unsigned*)regB;            // A..C alias: capture idx buf
                                                 //   (24 KB = regB+regC, dead in A..C)
    char* regD = smem + 56 * 1024;               // 4 KB: penalty hash
    int* hkey = (int*)regD;
    int* hval = (int*)(regD + 2 * 1024);
    __shared__ int wt_i[16];                     // wave totals (int scans)
    __shared__ float wt_f[16];                   // wave totals (float scan)
    __shared__ float esum_s, corr_s;
    __shared__ int bstar_s, lcnt_s, rb_s, pcnt_s, cap_s;

    int row = blockIdx.x, tid = threadIdx.x;
    int lane = tid & 63, wid = tid >> 6;
    for (int b = tid; b < NB; b += NT) hc[b] = 0u;
    if (tid == 0) {
        esum_s = 0.f; corr_s = 0.f; bstar_s = -1;
        lcnt_s = 0; rb_s = 0; pcnt_s = 0; cap_s = 0;
    }

    // ---- hash of penalty tokens ----
    for (int i = tid; i < HS; i += NT) { hkey[i] = -1; hval[i] = 0; }
    __syncthreads();
    const int* trow = tokens + (size_t)row * H;
    for (int i = tid; i < H; i += NT) {
        int v = trow[i];
        unsigned h = ((unsigned)v * 2654435761u) >> 23;
        while (true) {
            int prev = atomicCAS(&hkey[h], -1, v);
            if (prev == -1 || prev == v) { atomicAdd(&hval[h], 1); break; }
            h = (h + 1) & HM;
        }
    }
    __syncthreads();

    float t = temps[row];
    float topp = topp_v[row];              // hoisted: no global loads after
    float r = __fdiv_rn(1.0f, t);          // the zero-store burst below
    const float* lrow = logits + (size_t)row * V;
    const float4* l4p = (const float4*)lrow;
    float4* o4p = (float4*)(out + (size_t)row * V);
    const float4 z4 = make_float4(0.f, 0.f, 0.f, 0.f);
    int V4 = V >> 2;
    int ZITER = (V4 + NT - 1) / NT;        // zero-fill float4 steps per thread

    // ---- Phase A: read-only stream — hist + sum(exp) + optimistic capture --
    float es = 0.0f;
    int i = tid;
    for (; i + 7 * NT < V4; i += 8 * NT) {
        float4 arr[8];
#pragma unroll
        for (int q = 0; q < 8; ++q) arr[q] = l4p[i + q * NT];
#pragma unroll
        for (int q = 0; q < 8; ++q) {
            int vb = (i + q * NT) << 2;
#pragma unroll
            for (int j = 0; j < 4; ++j) {
                float l = (&arr[q].x)[j];
                float x = __fmul_rn(l, r);
                atomicAdd(&hc[mono_u32(x) >> BSHIFT], 1u);
                es += __expf(x);
                if (l >= CAPTHR) {
                    int pos = atomicAdd(&cap_s, 1);
                    if (pos < CAP2) cbuf[pos] = (unsigned)(vb + j);
                }
            }
        }
    }
    for (; i < V4; i += NT) {
        float4 A = l4p[i];
#pragma unroll
        for (int j = 0; j < 4; ++j) {
            float l = (&A.x)[j];
            float x = __fmul_rn(l, r);
            atomicAdd(&hc[mono_u32(x) >> BSHIFT], 1u);
            es += __expf(x);
            if (l >= CAPTHR) {
                int pos = atomicAdd(&cap_s, 1);
                if (pos < CAP2) cbuf[pos] = (unsigned)((i << 2) + j);
            }
        }
    }
    for (int v = (V4 << 2) + tid; v < V; v += NT) {
        float l = lrow[v];
        float x = __fmul_rn(l, r);
        atomicAdd(&hc[mono_u32(x) >> BSHIFT], 1u);
        es += __expf(x);
        if (l >= CAPTHR) {
            int pos = atomicAdd(&cap_s, 1);
            if (pos < CAP2) cbuf[pos] = (unsigned)v;
        }
    }
    for (int off = 32; off; off >>= 1) es += __shfl_down(es, off);
    if ((tid & 63) == 0) atomicAdd(&esum_s, es);
    __syncthreads();

    // ---- penalty corrections (<=200/row): move buckets, fix sum(exp) ----
    float pres = pres_v[row], freq = freq_v[row];
    int active = (pres >= 1e-5f) || (freq >= 1e-5f);
    float corr = 0.0f;
    if (active) {
        for (int s = tid; s < HS; s += NT) {
            int v = hkey[s];
            if (v >= 0) {
                int c = hval[s];
                float l = lrow[v];
                float x0 = __fmul_rn(l, r);
                float xp = compute_x(l, c, pres, freq, t);
                unsigned b0 = mono_u32(x0) >> BSHIFT;
                unsigned bp = mono_u32(xp) >> BSHIFT;
                if (b0 != bp) { atomicSub(&hc[b0], 1u); atomicAdd(&hc[bp], 1u); }
                corr += __expf(xp) - __expf(x0);
            }
        }
    }
    for (int off = 32; off; off >>= 1) corr += __shfl_down(corr, off);
    if ((tid & 63) == 0) atomicAdd(&corr_s, corr);
    __syncthreads();

    // ---- Phase B: coarse suffix scan (8/thread serial + wave shfl scan) ----
    const int BPT = NB / NT;   // 8
    int base = tid * BPT;
    int acc = 0;
#pragma unroll
    for (int q = BPT - 1; q >= 0; --q) { acc += (int)hc[base + q]; hc[base + q] = (unsigned)acc; }
    int k = topk_v[row];
    {
        int v = acc;
#pragma unroll
        for (int off = 1; off < 64; off <<= 1) {
            int o = __shfl_down(v, off);
            if (lane + off < 64) v += o;
        }
        if (lane == 0) wt_i[wid] = v;   // wave total
        __syncthreads();
        int above = v - acc;            // suffix of lanes > lane within wave
#pragma unroll
        for (int w = 0; w < 16; ++w) if (w > wid) above += wt_i[w];
        int best = -1;
#pragma unroll
        for (int q = BPT - 1; q >= 0; --q)
            if ((int)hc[base + q] + above >= k) { best = base + q; break; }
        if (best >= 0) atomicMax(&bstar_s, best);
    }
    __syncthreads();
    int bst = bstar_s - 2;               // slack: approx-vs-exact bucketing
    if (bst < 0) bst = 0;
    float Sp = esum_s + corr_s;
    int ccount = cap_s;
    __syncthreads();                     // hc dead; region A becomes skey

    // ---- skip test: captured set provably ⊇ {bucket(l*r) >= bst} ? ----
    // l < CAPTHR => fmul_rn(l,r) <= fmul_rn(CAPTHR,r)  (RN mult is monotone)
    // => bucket <= lb.  So lb < bst => nothing below CAPTHR can pass C's filter.
    int lb = (int)(mono_u32(__fmul_rn(CAPTHR, r)) >> BSHIFT);
    bool skip_c = (ccount <= CAP2) && (lb < bst);

    // ---- Phase C: candidate compaction ----
    if (skip_c) {
        // fast path: batched gather+filter of <=6144 captured indices
        unsigned myidx[6];
#pragma unroll
        for (int q = 0; q < 6; ++q) {
            int j2 = tid + q * NT;
            myidx[q] = (j2 < ccount) ? cbuf[j2] : 0xffffffffu;
        }
        float myl[6];
#pragma unroll
        for (int q = 0; q < 6; ++q)
            if (myidx[q] != 0xffffffffu) myl[q] = lrow[myidx[q]];
#pragma unroll
        for (int q = 0; q < 6; ++q) {
            if (myidx[q] != 0xffffffffu) {
                float l = myl[q];
                unsigned ua = mono_u32(__fmul_rn(l, r));
                if ((int)(ua >> BSHIFT) >= bst) {
                    unsigned ue = mono_u32(__fdiv_rn(l, t));   // exact key
                    int pos = atomicAdd(&lcnt_s, 1);
                    if (pos < CAP)
                        skey[pos] = ((ull)ue << 32) | (unsigned)~myidx[q];
                }
            }
        }
    } else {
        // fallback: full re-scan (L3-resident)
        i = tid;
        for (; i + 7 * NT < V4; i += 8 * NT) {
            float4 arr[8];
#pragma unroll
            for (int q = 0; q < 8; ++q) arr[q] = l4p[i + q * NT];
#pragma unroll
            for (int q = 0; q < 8; ++q) {
                int vb = (i + q * NT) << 2;
#pragma unroll
                for (int j = 0; j < 4; ++j) {
                    float l = (&arr[q].x)[j];
                    unsigned ua = mono_u32(__fmul_rn(l, r));
                    if ((int)(ua >> BSHIFT) >= bst) {
                        unsigned ue = mono_u32(__fdiv_rn(l, t));
                        int pos = atomicAdd(&lcnt_s, 1);
                        if (pos < CAP)
                            skey[pos] = ((ull)ue << 32) | (unsigned)~(unsigned)(vb + j);
                    }
                }
            }
        }
        for (; i < V4; i += NT) {
            float4 A = l4p[i];
#pragma unroll
            for (int j = 0; j < 4; ++j) {
                float l = (&A.x)[j];
                unsigned ua = mono_u32(__fmul_rn(l, r));
                if ((int)(ua >> BSHIFT) >= bst) {
                    unsigned ue = mono_u32(__fdiv_rn(l, t));
                    int pos = atomicAdd(&lcnt_s, 1);
                    if (pos < CAP)
                        skey[pos] = ((ull)ue << 32) | (unsigned)~(unsigned)((i << 2) + j);
                }
            }
        }
        for (int v = (V4 << 2) + tid; v < V; v += NT) {
            float l = lrow[v];
            unsigned ua = mono_u32(__fmul_rn(l, r));
            if ((int)(ua >> BSHIFT) >= bst) {
                unsigned ue = mono_u32(__fdiv_rn(l, t));
                int pos = atomicAdd(&lcnt_s, 1);
                if (pos < CAP)
                    skey[pos] = ((ull)ue << 32) | (unsigned)~(unsigned)v;
            }
        }
    }
    __syncthreads();
    int count = lcnt_s; if (count > CAP) count = CAP;

    // ---- Phase D: exact penalized keys (last dependent global LOADS) ----
    if (active) {
        for (int j = tid; j < count; j += NT) {
            unsigned idx = ~(unsigned)(skey[j] & 0xffffffffull);
            unsigned h = (idx * 2654435761u) >> 23;
            int c = 0;
            while (true) {
                int kk = hkey[h];
                if (kk == (int)idx) { c = hval[h]; break; }
                if (kk == -1) break;
                h = (h + 1) & HM;
            }
            if (c > 0) {
                float xp = compute_x(lrow[idx], c, pres, freq, t);
                skey[j] = ((ull)mono_u32(xp) << 32) | (unsigned)~idx;
            }
        }
    }

    // ---- zero-fill burst: fire-and-forget stores; they stay in flight
    // across all following bar_lds() barriers (no vmcnt drain) and flush
    // under the refined-cut + sort + phase-F LDS work. bar_full() before
    // the scatter orders zero-store -> scatter-store. ----
#pragma unroll 1
    for (int zc = 0; zc < ZITER; ++zc) {
        int p = tid + zc * NT;
        if (p < V4) o4p[p] = z4;
    }
    for (int v2 = (V4 << 2) + tid; v2 < V; v2 += NT)
        out[(size_t)row * V + v2] = 0.0f;
    bar_lds();

    // ---- refined cut, prune (LDS only) ----
    for (int g = tid; g < NRB; g += NT) rh[g] = 0u;
    bar_lds();
    int gmin = bst << 6;
    for (int j = tid; j < count; j += NT) {
        unsigned u = (unsigned)(skey[j] >> 32);
        int rel = (int)(u >> 13) - gmin;
        rel = rel < 0 ? 0 : (rel > NRB - 1 ? NRB - 1 : rel);
        atomicAdd(&rh[rel], 1u);
    }
    bar_lds();
    {   // refined suffix scan (2/thread serial + wave shfl scan)
        int b2i = tid * 2;
        int a2 = (int)rh[b2i + 1];
        rh[b2i + 1] = (unsigned)a2;
        a2 += (int)rh[b2i];
        rh[b2i] = (unsigned)a2;
        int v = a2;
#pragma unroll
        for (int off = 1; off < 64; off <<= 1) {
            int o = __shfl_down(v, off);
            if (lane + off < 64) v += o;
        }
        if (lane == 0) wt_i[wid] = v;
        bar_lds();
        int above = v - a2;
#pragma unroll
        for (int w = 0; w < 16; ++w) if (w > wid) above += wt_i[w];
        int best = -1;
        if ((int)rh[b2i + 1] + above >= k) best = b2i + 1;
        else if ((int)rh[b2i] + above >= k) best = b2i;
        if (best >= 0) atomicMax(&rb_s, best);
    }
    bar_lds();
    int rb = rb_s;
    for (int j = tid; j < count; j += NT) {
        unsigned u = (unsigned)(skey[j] >> 32);
        int rel = (int)(u >> 13) - gmin;
        rel = rel < 0 ? 0 : (rel > NRB - 1 ? NRB - 1 : rel);
        if (rel >= rb) {
            int pos = atomicAdd(&pcnt_s, 1);
            if (pos < PCAP) tmpc[pos] = skey[j];
        }
    }
    bar_lds();
    int count2 = pcnt_s;
    if (count2 <= PCAP) {   // pruned set is rank-preserving (upward-closed in u)
        for (int j = tid; j < count2; j += NT) skey[j] = tmpc[j];
        count = count2;
    }
    bar_lds();

    // ---- Phase E: bitonic sort descending (LDS only, raw barriers) ----
    int m = 1; while (m < count) m <<= 1;
    for (int j = count + tid; j < m; j += NT) skey[j] = 0ull;
    bar_lds();
    for (int kk = 2; kk <= m; kk <<= 1) {
        for (int jj = kk >> 1; jj > 0; jj >>= 1) {
            for (int i2 = tid; i2 < m; i2 += NT) {
                int ixj = i2 ^ jj;
                if (ixj > i2) {
                    ull A = skey[i2], B = skey[ixj];
                    bool up = ((i2 & kk) != 0);
                    if ((A > B) == up) { skey[i2] = B; skey[ixj] = A; }
                }
            }
            bar_lds();
        }
    }

    // ---- Phase F: exp, exact cumsum (wave shfl scan), select, scatter ----
    for (int j = tid; j < CAP; j += NT)
        se[j] = (j < count) ? __expf(inv_mono((unsigned)(skey[j] >> 32))) : 0.0f;
    bar_lds();
    int j0 = tid << 2;
    float e0 = se[j0], e1 = se[j0 + 1], e2 = se[j0 + 2], e3 = se[j0 + 3];
    float c0 = e0, c1 = c0 + e1, c2 = c1 + e2, c3 = c2 + e3;
    float vf = c3;
#pragma unroll
    for (int off = 1; off < 64; off <<= 1) {
        float o = __shfl_up(vf, off);
        if (lane >= off) vf += o;
    }
    if (lane == 63) wt_f[wid] = vf;      // wave total
    bar_lds();
    float pre = vf - c3;                 // exclusive prefix within wave
#pragma unroll
    for (int w = 0; w < 16; ++w) if (w < wid) pre += wt_f[w];

    // drain zero-stores (overlapped with everything since phase D), then scatter
    bar_full();

    float pS = topp * Sp;
    float inc[4] = {pre + c0, pre + c1, pre + c2, pre + c3};
    float ee[4] = {e0, e1, e2, e3};
#pragma unroll
    for (int q = 0; q < 4; ++q) {
        int j = j0 + q;
        if (j < count) {
            float e = ee[q];
            float excl = __fsub_rn(inc[q], e);
            if ((j < k) && (excl <= pS)) {
                unsigned idx = ~(unsigned)(skey[j] & 0xffffffffull);
                out[(size_t)row * V + idx] = __fdiv_rn(e, Sp);
            }
        }
    }
}

extern "C" void kernel_launch(void* const* d_in, const int* in_sizes, int n_in,
                              void* d_out, int out_size, void* d_ws, size_t ws_size,
                              hipStream_t stream) {
    const float* logits = (const float*)d_in[0];
    const float* pres   = (const float*)d_in[1];
    const float* freq   = (const float*)d_in[2];
    const float* temps  = (const float*)d_in[3];
    const float* topps  = (const float*)d_in[4];
    const int*   tokens = (const int*)d_in[5];
    const int*   topks  = (const int*)d_in[6];
    int N = in_sizes[1];
    int V = in_sizes[0] / N;
    int H = in_sizes[5] / N;
    float* out = (float*)d_out;

    k_fused<<<N, NT, 0, stream>>>(logits, tokens, pres, freq, temps, topps,
                                  topks, V, H, out);
}

// Round 6
// 275.150 us; speedup vs baseline: 1.0572x; 1.0572x over previous
//
#include <hip/hip_runtime.h>
#include <stdint.h>

#define NB 8192          // coarse buckets (top 13 bits of monotone key)
#define BSHIFT 19
#define HS 512
#define HM 511
#define CAP 4096         // candidate capacity
#define CAP2 6144        // optimistic capture capacity (= 6*NT, 24 KB as u32)
#define PCAP 2048        // pruned-candidate capacity
#define NRB 2048         // refined buckets
#define NT 1024
#define CAPTHR 1.75f     // capture threshold (raw-logit space)

typedef unsigned long long ull;

// ---- raw barrier, LDS-ordering only (HW-validated in round 5): does NOT
// drain vmcnt, so paced zero-stores stay in flight across it ----
__device__ __forceinline__ void bar_lds() {
    asm volatile("s_waitcnt lgkmcnt(0)" ::: "memory");
    __builtin_amdgcn_s_barrier();
    __builtin_amdgcn_sched_barrier(0);
}

// ---- monotonic float<->uint mapping: larger float => larger uint ----
__device__ __forceinline__ unsigned mono_u32(float x) {
    unsigned b = __float_as_uint(x);
    return (b & 0x80000000u) ? ~b : (b | 0x80000000u);
}
__device__ __forceinline__ float inv_mono(unsigned u) {
    unsigned b = (u & 0x80000000u) ? (u & 0x7fffffffu) : ~u;
    return __uint_as_float(b);
}

// numpy op order: pen = freq*cnt + pres*(cnt>0); x = (l - pen) / t
__device__ __forceinline__ float compute_x(float l, int cnt,
                                           float pres, float freq, float t) {
    float pen = __fadd_rn(__fmul_rn(freq, (float)cnt), (cnt > 0) ? pres : 0.0f);
    return __fdiv_rn(__fsub_rn(l, pen), t);
}

// in-register bitonic stages (wave owns 128 contiguous elements; lane l
// holds elements e0=2l, e0+1 of its chunk). Exact same compare network as
// the LDS version: lower-index element keeps max when (idx&kk)==0 (desc).
#define SHFL_STAGE(kk, jj) do {                                              \
    int _s = (jj) >> 1;                                                      \
    ull _pA = __shfl_xor(A, _s), _pB = __shfl_xor(B, _s);                    \
    bool _keepmn = (((e0 & (jj)) == 0) == ((e0 & (kk)) != 0));               \
    ull _mnA = (A < _pA) ? A : _pA, _mxA = (A < _pA) ? _pA : A;              \
    ull _mnB = (B < _pB) ? B : _pB, _mxB = (B < _pB) ? _pB : B;              \
    A = _keepmn ? _mnA : _mxA;  B = _keepmn ? _mnB : _mxB;                   \
} while (0)
#define PAIR_STAGE(kk) do {                                                  \
    bool _up = ((e0 & (kk)) != 0);                                           \
    ull _mn = (A < B) ? A : B, _mx = (A < B) ? B : A;                        \
    A = _up ? _mn : _mx;  B = _up ? _mx : _mn;                               \
} while (0)
// paced zero-fill: issue nn fire-and-forget stores (16 KB/CU each) — issue
// rate matched to drain rate so the VMEM queue never backs up (round-5 lesson)
#define ZDRIB(nn) do {                                                       \
    for (int _z = 0; _z < (nn) && zc < ZITER; ++_z) {                        \
        int _p = tid + zc * NT; if (_p < V4) o4p[_p] = z4; ++zc;             \
    }                                                                        \
} while (0)

__global__ __launch_bounds__(NT) void k_fused(
    const float* __restrict__ logits, const int* __restrict__ tokens,
    const float* __restrict__ pres_v, const float* __restrict__ freq_v,
    const float* __restrict__ temps, const float* __restrict__ topp_v,
    const int* __restrict__ topk_v, int V, int H, float* __restrict__ out)
{
    // ---- 60 KB LDS, phase-wise region reuse (validated budget) ----
    __shared__ __align__(16) char smem[(32 + 16 + 8 + 4) * 1024];
    unsigned* hc = (unsigned*)smem;              // A: coarse hist (phases A,B)
    ull* skey = (ull*)smem;                      // A alias: candidates (C..F)
    char* regB = smem + 32 * 1024;               // 16 KB
    float* se = (float*)regB;                    //   phase F exp values
    ull* tmpc = (ull*)regB;                      //   phase D compaction buffer
    char* regC = smem + 48 * 1024;               // 8 KB
    unsigned* rh = (unsigned*)regC;              //   phase D refined hist
    unsigned* cbuf = (unsigned*)regB;            // A..C alias: capture idx buf
    char* regD = smem + 56 * 1024;               // 4 KB: penalty hash
    int* hkey = (int*)regD;
    int* hval = (int*)(regD + 2 * 1024);
    __shared__ int wt_i[16];                     // wave totals (int scans)
    __shared__ float wt_f[16];                   // wave totals (float scan)
    __shared__ float esum_s, corr_s;
    __shared__ int bstar_s, lcnt_s, rb_s, pcnt_s, cap_s;

    int row = blockIdx.x, tid = threadIdx.x;
    int lane = tid & 63, wid = tid >> 6;
    for (int b = tid; b < NB; b += NT) hc[b] = 0u;
    if (tid == 0) {
        esum_s = 0.f; corr_s = 0.f; bstar_s = -1;
        lcnt_s = 0; rb_s = 0; pcnt_s = 0; cap_s = 0;
    }

    // ---- hash of penalty tokens ----
    for (int i = tid; i < HS; i += NT) { hkey[i] = -1; hval[i] = 0; }
    __syncthreads();
    const int* trow = tokens + (size_t)row * H;
    for (int i = tid; i < H; i += NT) {
        int v = trow[i];
        unsigned h = ((unsigned)v * 2654435761u) >> 23;
        while (true) {
            int prev = atomicCAS(&hkey[h], -1, v);
            if (prev == -1 || prev == v) { atomicAdd(&hval[h], 1); break; }
            h = (h + 1) & HM;
        }
    }
    __syncthreads();

    float t = temps[row];
    float topp = topp_v[row];
    float r = __fdiv_rn(1.0f, t);          // identical approx in both streams
    const float* lrow = logits + (size_t)row * V;
    const float4* l4p = (const float4*)lrow;
    float4* o4p = (float4*)(out + (size_t)row * V);
    const float4 z4 = make_float4(0.f, 0.f, 0.f, 0.f);
    int V4 = V >> 2;
    int ZITER = (V4 + NT - 1) / NT;        // zero-fill float4 steps per thread
    int zc = 0;                            // zero-fill cursor

    // ---- Phase A: read-only stream — hist + sum(exp) + optimistic capture --
    float es = 0.0f;
    int i = tid;
    for (; i + 7 * NT < V4; i += 8 * NT) {
        float4 arr[8];
#pragma unroll
        for (int q = 0; q < 8; ++q) arr[q] = l4p[i + q * NT];
#pragma unroll
        for (int q = 0; q < 8; ++q) {
            int vb = (i + q * NT) << 2;
#pragma unroll
            for (int j = 0; j < 4; ++j) {
                float l = (&arr[q].x)[j];
                float x = __fmul_rn(l, r);
                atomicAdd(&hc[mono_u32(x) >> BSHIFT], 1u);
                es += __expf(x);
                if (l >= CAPTHR) {
                    int pos = atomicAdd(&cap_s, 1);
                    if (pos < CAP2) cbuf[pos] = (unsigned)(vb + j);
                }
            }
        }
    }
    for (; i < V4; i += NT) {
        float4 A4 = l4p[i];
#pragma unroll
        for (int j = 0; j < 4; ++j) {
            float l = (&A4.x)[j];
            float x = __fmul_rn(l, r);
            atomicAdd(&hc[mono_u32(x) >> BSHIFT], 1u);
            es += __expf(x);
            if (l >= CAPTHR) {
                int pos = atomicAdd(&cap_s, 1);
                if (pos < CAP2) cbuf[pos] = (unsigned)((i << 2) + j);
            }
        }
    }
    for (int v = (V4 << 2) + tid; v < V; v += NT) {
        float l = lrow[v];
        float x = __fmul_rn(l, r);
        atomicAdd(&hc[mono_u32(x) >> BSHIFT], 1u);
        es += __expf(x);
        if (l >= CAPTHR) {
            int pos = atomicAdd(&cap_s, 1);
            if (pos < CAP2) cbuf[pos] = (unsigned)v;
        }
    }
    for (int off = 32; off; off >>= 1) es += __shfl_down(es, off);
    if ((tid & 63) == 0) atomicAdd(&esum_s, es);
    __syncthreads();

    // ---- penalty corrections (<=200/row): move buckets, fix sum(exp) ----
    float pres = pres_v[row], freq = freq_v[row];
    int active = (pres >= 1e-5f) || (freq >= 1e-5f);
    float corr = 0.0f;
    if (active) {
        for (int s = tid; s < HS; s += NT) {
            int v = hkey[s];
            if (v >= 0) {
                int c = hval[s];
                float l = lrow[v];
                float x0 = __fmul_rn(l, r);
                float xp = compute_x(l, c, pres, freq, t);
                unsigned b0 = mono_u32(x0) >> BSHIFT;
                unsigned bp = mono_u32(xp) >> BSHIFT;
                if (b0 != bp) { atomicSub(&hc[b0], 1u); atomicAdd(&hc[bp], 1u); }
                corr += __expf(xp) - __expf(x0);
            }
        }
    }
    for (int off = 32; off; off >>= 1) corr += __shfl_down(corr, off);
    if ((tid & 63) == 0) atomicAdd(&corr_s, corr);
    __syncthreads();

    // ---- Phase B: coarse suffix scan (8/thread serial + wave shfl scan) ----
    const int BPT = NB / NT;   // 8
    int base = tid * BPT;
    int acc = 0;
#pragma unroll
    for (int q = BPT - 1; q >= 0; --q) { acc += (int)hc[base + q]; hc[base + q] = (unsigned)acc; }
    int k = topk_v[row];
    {
        int v = acc;
#pragma unroll
        for (int off = 1; off < 64; off <<= 1) {
            int o = __shfl_down(v, off);
            if (lane + off < 64) v += o;
        }
        if (lane == 0) wt_i[wid] = v;   // wave total
        __syncthreads();
        int above = v - acc;            // suffix of lanes > lane within wave
#pragma unroll
        for (int w = 0; w < 16; ++w) if (w > wid) above += wt_i[w];
        int best = -1;
#pragma unroll
        for (int q = BPT - 1; q >= 0; --q)
            if ((int)hc[base + q] + above >= k) { best = base + q; break; }
        if (best >= 0) atomicMax(&bstar_s, best);
    }
    __syncthreads();
    int bst = bstar_s - 2;               // slack: approx-vs-exact bucketing
    if (bst < 0) bst = 0;
    float Sp = esum_s + corr_s;
    int ccount = cap_s;
    __syncthreads();                     // hc dead; region A becomes skey

    // ---- skip test: captured set provably ⊇ {bucket(l*r) >= bst} ? ----
    int lb = (int)(mono_u32(__fmul_rn(CAPTHR, r)) >> BSHIFT);
    bool skip_c = (ccount <= CAP2) && (lb < bst);

    // ---- Phase C: candidate compaction ----
    if (skip_c) {
        unsigned myidx[6];
#pragma unroll
        for (int q = 0; q < 6; ++q) {
            int j2 = tid + q * NT;
            myidx[q] = (j2 < ccount) ? cbuf[j2] : 0xffffffffu;
        }
        float myl[6];
#pragma unroll
        for (int q = 0; q < 6; ++q)
            if (myidx[q] != 0xffffffffu) myl[q] = lrow[myidx[q]];
#pragma unroll
        for (int q = 0; q < 6; ++q) {
            if (myidx[q] != 0xffffffffu) {
                float l = myl[q];
                unsigned ua = mono_u32(__fmul_rn(l, r));
                if ((int)(ua >> BSHIFT) >= bst) {
                    unsigned ue = mono_u32(__fdiv_rn(l, t));   // exact key
                    int pos = atomicAdd(&lcnt_s, 1);
                    if (pos < CAP)
                        skey[pos] = ((ull)ue << 32) | (unsigned)~myidx[q];
                }
            }
        }
    } else {
        // fallback: full re-scan (L3-resident)
        i = tid;
        for (; i + 7 * NT < V4; i += 8 * NT) {
            float4 arr[8];
#pragma unroll
            for (int q = 0; q < 8; ++q) arr[q] = l4p[i + q * NT];
#pragma unroll
            for (int q = 0; q < 8; ++q) {
                int vb = (i + q * NT) << 2;
#pragma unroll
                for (int j = 0; j < 4; ++j) {
                    float l = (&arr[q].x)[j];
                    unsigned ua = mono_u32(__fmul_rn(l, r));
                    if ((int)(ua >> BSHIFT) >= bst) {
                        unsigned ue = mono_u32(__fdiv_rn(l, t));
                        int pos = atomicAdd(&lcnt_s, 1);
                        if (pos < CAP)
                            skey[pos] = ((ull)ue << 32) | (unsigned)~(unsigned)(vb + j);
                    }
                }
            }
        }
        for (; i < V4; i += NT) {
            float4 A4 = l4p[i];
#pragma unroll
            for (int j = 0; j < 4; ++j) {
                float l = (&A4.x)[j];
                unsigned ua = mono_u32(__fmul_rn(l, r));
                if ((int)(ua >> BSHIFT) >= bst) {
                    unsigned ue = mono_u32(__fdiv_rn(l, t));
                    int pos = atomicAdd(&lcnt_s, 1);
                    if (pos < CAP)
                        skey[pos] = ((ull)ue << 32) | (unsigned)~(unsigned)((i << 2) + j);
                }
            }
        }
        for (int v = (V4 << 2) + tid; v < V; v += NT) {
            float l = lrow[v];
            unsigned ua = mono_u32(__fmul_rn(l, r));
            if ((int)(ua >> BSHIFT) >= bst) {
                unsigned ue = mono_u32(__fdiv_rn(l, t));
                int pos = atomicAdd(&lcnt_s, 1);
                if (pos < CAP)
                    skey[pos] = ((ull)ue << 32) | (unsigned)~(unsigned)v;
            }
        }
    }
    __syncthreads();
    int count = lcnt_s; if (count > CAP) count = CAP;

    // ---- Phase D: exact penalized keys (last dependent global loads) ----
    if (active) {
        for (int j = tid; j < count; j += NT) {
            unsigned idx = ~(unsigned)(skey[j] & 0xffffffffull);
            unsigned h = (idx * 2654435761u) >> 23;
            int c = 0;
            while (true) {
                int kk = hkey[h];
                if (kk == (int)idx) { c = hval[h]; break; }
                if (kk == -1) break;
                h = (h + 1) & HM;
            }
            if (c > 0) {
                float xp = compute_x(lrow[idx], c, pres, freq, t);
                skey[j] = ((ull)mono_u32(xp) << 32) | (unsigned)~idx;
            }
        }
    }
    ZDRIB(2); bar_lds();                 // publish D; start paced zero-fill

    // ---- refined cut, prune (LDS only; bar_lds keeps stores in flight) ----
    for (int g = tid; g < NRB; g += NT) rh[g] = 0u;
    ZDRIB(2); bar_lds();
    int gmin = bst << 6;
    for (int j = tid; j < count; j += NT) {
        unsigned u = (unsigned)(skey[j] >> 32);
        int rel = (int)(u >> 13) - gmin;
        rel = rel < 0 ? 0 : (rel > NRB - 1 ? NRB - 1 : rel);
        atomicAdd(&rh[rel], 1u);
    }
    ZDRIB(2); bar_lds();
    {   // refined suffix scan (2/thread serial + wave shfl scan)
        int b2i = tid * 2;
        int a2 = (int)rh[b2i + 1];
        rh[b2i + 1] = (unsigned)a2;
        a2 += (int)rh[b2i];
        rh[b2i] = (unsigned)a2;
        int v = a2;
#pragma unroll
        for (int off = 1; off < 64; off <<= 1) {
            int o = __shfl_down(v, off);
            if (lane + off < 64) v += o;
        }
        if (lane == 0) wt_i[wid] = v;
        ZDRIB(2); bar_lds();
        int above = v - a2;
#pragma unroll
        for (int w = 0; w < 16; ++w) if (w > wid) above += wt_i[w];
        int best = -1;
        if ((int)rh[b2i + 1] + above >= k) best = b2i + 1;
        else if ((int)rh[b2i] + above >= k) best = b2i;
        if (best >= 0) atomicMax(&rb_s, best);
    }
    ZDRIB(2); bar_lds();
    int rb = rb_s;
    for (int j = tid; j < count; j += NT) {
        unsigned u = (unsigned)(skey[j] >> 32);
        int rel = (int)(u >> 13) - gmin;
        rel = rel < 0 ? 0 : (rel > NRB - 1 ? NRB - 1 : rel);
        if (rel >= rb) {
            int pos = atomicAdd(&pcnt_s, 1);
            if (pos < PCAP) tmpc[pos] = skey[j];
        }
    }
    ZDRIB(2); bar_lds();
    int count2 = pcnt_s;
    if (count2 <= PCAP) {   // pruned set is rank-preserving (upward-closed in u)
        for (int j = tid; j < count2; j += NT) skey[j] = tmpc[j];
        count = count2;
    }
    ZDRIB(2); bar_lds();

    // ---- Phase E: bitonic sort descending ----
    if (count <= PCAP) {
        // fast path: fixed M=2048, wave-chunked register sort.
        // Stages jj<=64 run in registers via shfl (no barriers); only the
        // 10 cross-wave stages + per-level handoffs barrier: 15 vs 66.
        const int M = 2048;
        for (int j = count + tid; j < M; j += NT) skey[j] = 0ull;
        ZDRIB(2); bar_lds();
        int e0 = (wid << 7) + (lane << 1);   // wave chunk 128, 2 elems/lane
        ull A = skey[e0], B = skey[e0 + 1];
        ZDRIB(2);
        // levels 2..128: fully in registers (28 stages, zero barriers)
        for (int kk = 2; kk <= 128; kk <<= 1) {
            for (int jj = kk >> 1; jj >= 2; jj >>= 1) SHFL_STAGE(kk, jj);
            PAIR_STAGE(kk);
        }
        // levels 256..2048: cross-wave stages in LDS, tails in registers
        for (int kk = 256; kk <= 2048; kk <<= 1) {
            skey[e0] = A; skey[e0 + 1] = B;
            ZDRIB(2); bar_lds();
            for (int jj = kk >> 1; jj >= 128; jj >>= 1) {
                for (int i2 = tid; i2 < M; i2 += NT) {
                    int ixj = i2 ^ jj;
                    if (ixj > i2) {
                        ull X = skey[i2], Y = skey[ixj];
                        bool up = ((i2 & kk) != 0);
                        if ((X > Y) == up) { skey[i2] = Y; skey[ixj] = X; }
                    }
                }
                ZDRIB(2); bar_lds();
            }
            A = skey[e0]; B = skey[e0 + 1];
            for (int jj = 64; jj >= 2; jj >>= 1) SHFL_STAGE(kk, jj);
            PAIR_STAGE(kk);
        }
        skey[e0] = A; skey[e0 + 1] = B;
        // published to phase F by the catch-up __syncthreads below
    } else {
        // rare fallback (count in (PCAP, CAP]): generic LDS bitonic
        int m = 1; while (m < count) m <<= 1;
        for (int j = count + tid; j < m; j += NT) skey[j] = 0ull;
        __syncthreads();
        for (int kk = 2; kk <= m; kk <<= 1) {
            for (int jj = kk >> 1; jj > 0; jj >>= 1) {
                for (int i2 = tid; i2 < m; i2 += NT) {
                    int ixj = i2 ^ jj;
                    if (ixj > i2) {
                        ull X = skey[i2], Y = skey[ixj];
                        bool up = ((i2 & kk) != 0);
                        if ((X > Y) == up) { skey[i2] = Y; skey[ixj] = X; }
                    }
                }
                __syncthreads();
            }
        }
    }

    // catch-up zero-fill; the __syncthreads drains vmcnt (zero-stores ordered
    // before scatter) and publishes the final skey state for phase F
    for (; zc < ZITER; ++zc) {
        int p = tid + zc * NT;
        if (p < V4) o4p[p] = z4;
    }
    for (int v2 = (V4 << 2) + tid; v2 < V; v2 += NT)
        out[(size_t)row * V + v2] = 0.0f;
    __syncthreads();

    // ---- Phase F: exp, exact cumsum (wave shfl scan), select, scatter ----
    for (int j = tid; j < CAP; j += NT)
        se[j] = (j < count) ? __expf(inv_mono((unsigned)(skey[j] >> 32))) : 0.0f;
    __syncthreads();
    int j0 = tid << 2;
    float e0f = se[j0], e1 = se[j0 + 1], e2 = se[j0 + 2], e3 = se[j0 + 3];
    float c0 = e0f, c1 = c0 + e1, c2 = c1 + e2, c3 = c2 + e3;
    float vf = c3;
#pragma unroll
    for (int off = 1; off < 64; off <<= 1) {
        float o = __shfl_up(vf, off);
        if (lane >= off) vf += o;
    }
    if (lane == 63) wt_f[wid] = vf;      // wave total
    __syncthreads();
    float pre = vf - c3;                 // exclusive prefix within wave
#pragma unroll
    for (int w = 0; w < 16; ++w) if (w < wid) pre += wt_f[w];

    float pS = topp * Sp;
    float inc[4] = {pre + c0, pre + c1, pre + c2, pre + c3};
    float ee[4] = {e0f, e1, e2, e3};
#pragma unroll
    for (int q = 0; q < 4; ++q) {
        int j = j0 + q;
        if (j < count) {
            float e = ee[q];
            float excl = __fsub_rn(inc[q], e);
            if ((j < k) && (excl <= pS)) {
                unsigned idx = ~(unsigned)(skey[j] & 0xffffffffull);
                out[(size_t)row * V + idx] = __fdiv_rn(e, Sp);
            }
        }
    }
}

extern "C" void kernel_launch(void* const* d_in, const int* in_sizes, int n_in,
                              void* d_out, int out_size, void* d_ws, size_t ws_size,
                              hipStream_t stream) {
    const float* logits = (const float*)d_in[0];
    const float* pres   = (const float*)d_in[1];
    const float* freq   = (const float*)d_in[2];
    const float* temps  = (const float*)d_in[3];
    const float* topps  = (const float*)d_in[4];
    const int*   tokens = (const int*)d_in[5];
    const int*   topks  = (const int*)d_in[6];
    int N = in_sizes[1];
    int V = in_sizes[0] / N;
    int H = in_sizes[5] / N;
    float* out = (float*)d_out;

    k_fused<<<N, NT, 0, stream>>>(logits, tokens, pres, freq, temps, topps,
                                  topks, V, H, out);
}